// Round 3
// baseline (87.685 us; speedup 1.0000x reference)
//
#include <hip/hip_runtime.h>
#include <math.h>

// Problem constants (from reference setup_inputs)
#define BATCH 64
#define NPATCH 784
#define DIM 768
#define KSEL 392          // int(784 * 0.5)
#define SIDE 28
#define HWDIM 448
#define NPIX (HWDIM*HWDIM)     // 200704
#define PARTS 49               // blocks per batch for COG partial reduction
#define PIX_PER_PART (NPIX/PARTS)  // 4096
#define GSPLIT 4               // selection blocks per batch
#define IPB 196                // elements per selection block (784/4)

// native vector type usable with __builtin_nontemporal_*
typedef float f4v __attribute__((ext_vector_type(4)));

// ---------------------------------------------------------------------------
// Kernel 1: partial COG sums per (batch, part). Deterministic fixed-order
// double accumulation; per-element float32 products emulate numpy's
// (line_drawing * y) rounding before the sum.
// ---------------------------------------------------------------------------
__global__ __launch_bounds__(256) void cog_partial(const float* __restrict__ ld,
                                                   double* __restrict__ part) {
    const int blk = blockIdx.x;
    const int b = blk / PARTS;
    const int p = blk % PARTS;
    const int t = threadIdx.x;

    const float* base = ld + (size_t)b * NPIX + (size_t)p * PIX_PER_PART;
    double s = 0.0, sy = 0.0, sx = 0.0;

    // 4096 pixels per part = 1024 float4; 256 threads x 4 float4 each.
    // 448 % 4 == 0 so each float4 stays within one image row.
    #pragma unroll
    for (int r = 0; r < 4; ++r) {
        const int f4 = r * 256 + t;                 // 0..1023
        const int pix = p * PIX_PER_PART + f4 * 4;  // within-batch pixel idx
        const f4v v = __builtin_nontemporal_load(reinterpret_cast<const f4v*>(base) + f4);
        const int i = pix / HWDIM;
        const int j = pix - i * HWDIM;
        // linspace(0,1,448)[i] as numpy computes it: f32(i/447)
        const float yf = (float)((double)i / 447.0);
        const float x0 = (float)((double)(j + 0) / 447.0);
        const float x1 = (float)((double)(j + 1) / 447.0);
        const float x2 = (float)((double)(j + 2) / 447.0);
        const float x3 = (float)((double)(j + 3) / 447.0);
        s  += (double)v.x + (double)v.y + (double)v.z + (double)v.w;
        sy += (double)__fmul_rn(v.x, yf) + (double)__fmul_rn(v.y, yf)
            + (double)__fmul_rn(v.z, yf) + (double)__fmul_rn(v.w, yf);
        sx += (double)__fmul_rn(v.x, x0) + (double)__fmul_rn(v.y, x1)
            + (double)__fmul_rn(v.z, x2) + (double)__fmul_rn(v.w, x3);
    }

    __shared__ double red[3 * 256];
    red[t] = s; red[256 + t] = sy; red[512 + t] = sx;
    __syncthreads();
    for (int off = 128; off > 0; off >>= 1) {
        if (t < off) {
            red[t]       += red[t + off];
            red[256 + t] += red[256 + t + off];
            red[512 + t] += red[512 + t + off];
        }
        __syncthreads();
    }
    if (t == 0) {
        double* dst = part + (size_t)(b * PARTS + p) * 3;
        dst[0] = red[0]; dst[1] = red[256]; dst[2] = red[512];
    }
}

// ---------------------------------------------------------------------------
// Kernel 2: fused COG-combine + selection. Each of the 4 blocks per batch
// redundantly (and deterministically: fixed tree order, identical code+data)
// reduces the 49 partials, then computes weighted[784] in LDS and ranks its
// 196 elements with float4 LDS broadcast reads. Stable rank exactly
// reproduces lax.top_k tie-breaking and the combined
// (ascending-above, then masked-top-k) selection path.
// ---------------------------------------------------------------------------
__global__ __launch_bounds__(256) void select_k(const float* __restrict__ scores,
                                                const double* __restrict__ part,
                                                int* __restrict__ sel) {
    const int blk = blockIdx.x;
    const int b = blk / GSPLIT;
    const int g = blk % GSPLIT;
    const int t = threadIdx.x;

    __shared__ alignas(16) float sw[NPATCH];
    __shared__ double sd[3][64];
    __shared__ float scog[2];
    __shared__ int redc[256];

    // --- COG combine (deterministic fixed-order tree over 49 partials) ---
    if (t < 64) {
        if (t < PARTS) {
            const double* src = part + (size_t)(b * PARTS + t) * 3;
            sd[0][t] = src[0]; sd[1][t] = src[1]; sd[2][t] = src[2];
        } else {
            sd[0][t] = 0.0; sd[1][t] = 0.0; sd[2][t] = 0.0;
        }
    }
    __syncthreads();
    for (int off = 32; off > 0; off >>= 1) {
        if (t < off) {
            sd[0][t] += sd[0][t + off];
            sd[1][t] += sd[1][t + off];
            sd[2][t] += sd[2][t + off];
        }
        __syncthreads();
    }
    if (t == 0) {
        // reference: total = sum + 1e-6 (f32); cog = num / total (f32)
        const float total = __fadd_rn((float)sd[0][0], 1e-6f);
        scog[0] = __fdiv_rn((float)sd[1][0], total);   // cy
        scog[1] = __fdiv_rn((float)sd[2][0], total);   // cx
    }
    __syncthreads();
    const float cy = scog[0];
    const float cx = scog[1];

    // --- weighted scores ---
    int local_above = 0;
    for (int n = t; n < NPATCH; n += 256) {
        const int r = n / SIDE;
        const int c = n - r * SIDE;
        // linspace(0,1,28)[i] = f32(i/27)
        const float gy = (float)((double)r / 27.0);
        const float gx = (float)((double)c / 27.0);
        const float dy = gy - cy;
        const float dx = gx - cx;
        // emulate numpy: dy2, dx2 rounded separately, then summed (no FMA)
        const float dy2 = __fmul_rn(dy, dy);
        const float dx2 = __fmul_rn(dx, dx);
        const float d2 = __fadd_rn(dy2, dx2);
        // -d2 / 0.125 == -8*d2 exactly (power of two); exp in f64 then round
        const float w = (float)exp((double)(-8.0f * d2));
        const float wt = __fmul_rn(scores[(size_t)b * NPATCH + n], w);
        sw[n] = wt;
        local_above += (wt > 0.3f) ? 1 : 0;
    }

    redc[t] = local_above;
    __syncthreads();
    for (int off = 128; off > 0; off >>= 1) {
        if (t < off) redc[t] += redc[t + off];
        __syncthreads();
    }
    const int count = redc[0];
    const bool use_topk = (count == 0) || (count >= KSEL);

    // --- stable rank via float4 LDS broadcast reads ---
    const int i = g * IPB + t;
    if (t < IPB) {
        const float wi = sw[i];
        const bool above_i = wi > 0.3f;
        int r_all = 0, r_below = 0, r_pre = 0;
        const float4* swv = reinterpret_cast<const float4*>(sw);
        #pragma unroll 4
        for (int j4 = 0; j4 < NPATCH / 4; ++j4) {
            const float4 w4 = swv[j4];
            const int jb = j4 * 4;
            {
                const bool gt = (w4.x > wi) || ((w4.x == wi) && (jb + 0 < i));
                const bool aj = w4.x > 0.3f;
                r_all += gt; r_below += gt && !aj; r_pre += aj && (jb + 0 < i);
            }
            {
                const bool gt = (w4.y > wi) || ((w4.y == wi) && (jb + 1 < i));
                const bool aj = w4.y > 0.3f;
                r_all += gt; r_below += gt && !aj; r_pre += aj && (jb + 1 < i);
            }
            {
                const bool gt = (w4.z > wi) || ((w4.z == wi) && (jb + 2 < i));
                const bool aj = w4.z > 0.3f;
                r_all += gt; r_below += gt && !aj; r_pre += aj && (jb + 2 < i);
            }
            {
                const bool gt = (w4.w > wi) || ((w4.w == wi) && (jb + 3 < i));
                const bool aj = w4.w > 0.3f;
                r_all += gt; r_below += gt && !aj; r_pre += aj && (jb + 3 < i);
            }
        }
        int* selb = sel + (size_t)b * KSEL;
        if (use_topk) {
            if (r_all < KSEL) selb[r_all] = i;            // stable descending top-k
        } else if (above_i) {
            selb[r_pre] = i;                              // ascending above indices
        } else {
            const int pos = count + r_below;              // masked top-k remainder
            if (pos < KSEL) selb[pos] = i;
        }
    }
}

// ---------------------------------------------------------------------------
// Kernel 3: gather + add. 256 threads = 4 waves; one row per wave,
// 3 float4 per lane. Nontemporal on the streamed magno read and the
// write-once output.
// ---------------------------------------------------------------------------
__global__ __launch_bounds__(256) void gather_add(const float* __restrict__ magno,
                                                  const float* __restrict__ pos,
                                                  const int* __restrict__ sel,
                                                  float* __restrict__ out) {
    const int wid = threadIdx.x >> 6;
    const int lane = threadIdx.x & 63;
    const int row = blockIdx.x * 4 + wid;   // 0 .. BATCH*KSEL-1
    const int b = row / KSEL;
    const int s = sel[row];

    const f4v* src = reinterpret_cast<const f4v*>(magno + ((size_t)b * NPATCH + s) * DIM);
    const f4v* pp  = reinterpret_cast<const f4v*>(pos + (size_t)(s + 1) * DIM);
    f4v* dst = reinterpret_cast<f4v*>(out + (size_t)row * DIM);

    #pragma unroll
    for (int r = 0; r < 3; ++r) {
        const int c = r * 64 + lane;
        const f4v a = __builtin_nontemporal_load(src + c);
        const f4v p = pp[c];
        const f4v o = a + p;
        __builtin_nontemporal_store(o, dst + c);
    }
}

extern "C" void kernel_launch(void* const* d_in, const int* in_sizes, int n_in,
                              void* d_out, int out_size, void* d_ws, size_t ws_size,
                              hipStream_t stream) {
    const float* magno  = (const float*)d_in[0];  // [64, 784, 768]
    const float* vit    = (const float*)d_in[1];  // [1, 785, 768]
    const float* scores = (const float*)d_in[2];  // [64, 784]
    const float* ld     = (const float*)d_in[3];  // [64, 1, 448, 448]
    float* out = (float*)d_out;                   // [64, 392, 768]

    // workspace layout
    double* partials = (double*)d_ws;                                   // 64*49*3 doubles
    int*    sel = (int*)((char*)d_ws + (size_t)BATCH * PARTS * 3 * sizeof(double));

    cog_partial<<<dim3(BATCH * PARTS), dim3(256), 0, stream>>>(ld, partials);
    select_k<<<dim3(BATCH * GSPLIT), dim3(256), 0, stream>>>(scores, partials, sel);
    gather_add<<<dim3(BATCH * KSEL / 4), dim3(256), 0, stream>>>(magno, vit, sel, out);
}